// Round 3
// baseline (379.292 us; speedup 1.0000x reference)
//
#include <hip/hip_runtime.h>

#define BB 2
#define NN 4096
#define CIN 128
#define CC 64

typedef __attribute__((ext_vector_type(4))) float floatx4;
typedef __attribute__((ext_vector_type(8))) short short8;

__device__ __forceinline__ short f2bf(float f) {
    unsigned u = __float_as_uint(f);
    u += 0x7fffu + ((u >> 16) & 1u);   // RNE
    return (short)(u >> 16);
}

// sigmoid via v_exp_f32 + v_rcp_f32 (avoid precise-division expansion)
__device__ __forceinline__ float sigf(float x) {
    return __builtin_amdgcn_rcpf(1.0f + __expf(-x));
}

// lgkm-only barrier: ds ops visible, but vmcnt NOT drained -> NT stores and
// prefetched global loads stay in flight across the barrier.
__device__ __forceinline__ void lbar() {
    asm volatile("s_waitcnt lgkmcnt(0)" ::: "memory");
    __builtin_amdgcn_s_barrier();
}

// ---------------------------------------------------------------------------
// feat_v3: h = relu(relu(x@W1+b1)@W2+b2); u,v scalars; hT bf16 transposed.
// 16 rows/block, 256 threads, grid 512. hT written via LDS transpose tile
// -> coalesced short8 stores.
// ---------------------------------------------------------------------------
__global__ __launch_bounds__(256) void feat_v3(
    const float* __restrict__ x, const float* __restrict__ W1,
    const float* __restrict__ b1, const float* __restrict__ W2,
    const float* __restrict__ b2, const float* __restrict__ Wa,
    const float* __restrict__ ba,
    short* __restrict__ hT, float* __restrict__ u, float* __restrict__ v)
{
    __shared__ float W1s[CIN * CC];      // 32KB
    __shared__ float W2s[CC * CC];       // 16KB
    __shared__ float xs[16 * 132];       // 8.4KB padded
    __shared__ float h1s[16 * 68];       // 4.4KB padded
    __shared__ __align__(16) short hs[CC][16];  // 2KB bf16 transpose tile

    const int t = threadIdx.x;
    const int row0 = blockIdx.x * 16;

    {
        const floatx4* s1 = (const floatx4*)W1;
        floatx4* d1 = (floatx4*)W1s;
        for (int i = t; i < CIN * CC / 4; i += 256) d1[i] = s1[i];
        const floatx4* s2 = (const floatx4*)W2;
        floatx4* d2 = (floatx4*)W2s;
        for (int i = t; i < CC * CC / 4; i += 256) d2[i] = s2[i];
        const floatx4* sx = (const floatx4*)(x + (size_t)row0 * CIN);
        for (int i = t; i < 16 * CIN / 4; i += 256) {
            int rw = i >> 5, c4 = i & 31;
            *(floatx4*)(xs + rw * 132 + c4 * 4) = sx[i];
        }
    }
    __syncthreads();

    const int n  = t >> 4;       // 0..15 local row
    const int cg = t & 15;
    const int c0 = cg * 4;

    float acc[4];
#pragma unroll
    for (int i = 0; i < 4; i++) acc[i] = b1[c0 + i];
    for (int k = 0; k < CIN; k++) {
        float a = xs[n * 132 + k];
        const floatx4 w = *(const floatx4*)&W1s[k * CC + c0];
#pragma unroll
        for (int i = 0; i < 4; i++) acc[i] = fmaf(a, w[i], acc[i]);
    }
#pragma unroll
    for (int i = 0; i < 4; i++) h1s[n * 68 + c0 + i] = fmaxf(acc[i], 0.0f);
    __syncthreads();

    float acc2[4];
#pragma unroll
    for (int i = 0; i < 4; i++) acc2[i] = b2[c0 + i];
    for (int k = 0; k < CC; k++) {
        float a = h1s[n * 68 + k];
        const floatx4 w = *(const floatx4*)&W2s[k * CC + c0];
#pragma unroll
        for (int i = 0; i < 4; i++) acc2[i] = fmaf(a, w[i], acc2[i]);
    }
#pragma unroll
    for (int i = 0; i < 4; i++) acc2[i] = fmaxf(acc2[i], 0.0f);

    // stage bf16 transpose tile in LDS
#pragma unroll
    for (int i = 0; i < 4; i++) hs[c0 + i][n] = f2bf(acc2[i]);

    float pu = 0.0f, pv = 0.0f;
#pragma unroll
    for (int i = 0; i < 4; i++) {
        pu = fmaf(acc2[i], Wa[c0 + i], pu);
        pv = fmaf(acc2[i], Wa[CC + c0 + i], pv);
    }
    pu += __shfl_down(pu, 8, 16); pv += __shfl_down(pv, 8, 16);
    pu += __shfl_down(pu, 4, 16); pv += __shfl_down(pv, 4, 16);
    pu += __shfl_down(pu, 2, 16); pv += __shfl_down(pv, 2, 16);
    pu += __shfl_down(pu, 1, 16); pv += __shfl_down(pv, 1, 16);

    const int grow = row0 + n;
    if (cg == 0) { u[grow] = pu + ba[0]; v[grow] = pv; }

    __syncthreads();
    // coalesced hT write: 128 threads x short8 (16B), 2 per channel row
    if (t < 128) {
        const int c  = t >> 1;
        const int hf = t & 1;
        const int b   = row0 >> 12;
        const int nn0 = row0 & (NN - 1);
        *(short8*)(hT + ((size_t)(b * CC + c)) * NN + nn0 + hf * 8) =
            *(const short8*)&hs[c][hf * 8];
    }
}

// ---------------------------------------------------------------------------
// attn_v5: fused rowsum + attention, half-strip LDS staging.
// Block = 16 rows x all 4096 j, 512 threads (8 waves), grid 512 ->
//   2 blocks/CU, 16 waves/CU (LDS 70KB/block).
// Phase A: wave w owns rows 2w,2w+1; full-row sums, contiguous 32B/lane
//   reads, software-pipelined 2 stages deep (A/B named register sets).
// Phase B (x2 halves of 2048 j): sigmoid/normalize the wave's 2 rows
//   contiguously, NT-store aout, pack bf16 P into a 16x2048 LDS strip
//   (+8 pad: MFMA A-reads ~2-way conflicts). ONE lgkm barrier, then MFMA
//   sweep of the whole strip (wave = c-group x k-half, B-frags from
//   L2-resident hT), barrier, next half. Next half's first loads are
//   issued BEFORE the barrier so they drain under the MFMA phase.
// Epilogue: pair (cg,kh) add in LDS, direct hout store. No atomics.
// ---------------------------------------------------------------------------
__global__ __launch_bounds__(512, 4) void attn_v5(
    const float* __restrict__ adj, const float* __restrict__ u,
    const float* __restrict__ v, const short* __restrict__ hT,
    float* __restrict__ hout, float* __restrict__ aout)
{
    __shared__ __align__(16) short P[16][2056];   // 65.8KB, +8 pad
    __shared__ float red[4][16][17];              // 4.3KB epilogue

    const int wave = threadIdx.x >> 6;   // 0..7
    const int lane = threadIdx.x & 63;
    const int quad = lane >> 4;
    const int m16  = lane & 15;

    const int row0 = blockIdx.x * 16;
    const int b  = row0 >> 12;
    const int n0 = row0 & (NN - 1);
    const float* vb = v + b * NN;

    // rows owned by this wave for rowsum + sigmoid/normalize
    const int r0 = 2 * wave;
    const float u0 = u[b * NN + n0 + r0];
    const float u1 = u[b * NN + n0 + r0 + 1];
    const float* a0p = adj + ((size_t)(b * NN + n0 + r0)) * NN;
    const float* a1p = a0p + NN;
    float* o0p = aout + ((size_t)(b * NN + n0 + r0)) * NN;
    float* o1p = o0p + NN;

    // named 2-stage pipeline registers (6 x floatx4 per stage)
    floatx4 vA0, vA1, aA0, aA1, bA0, bA1;
    floatx4 vB0, vB1, aB0, aB1, bB0, bB1;

#define LDA(S, J) { const int j_ = (J) + lane * 8; \
    v##S##0 = *(const floatx4*)(vb  + j_); v##S##1 = *(const floatx4*)(vb  + j_ + 4); \
    a##S##0 = *(const floatx4*)(a0p + j_); a##S##1 = *(const floatx4*)(a0p + j_ + 4); \
    b##S##0 = *(const floatx4*)(a1p + j_); b##S##1 = *(const floatx4*)(a1p + j_ + 4); }

#define SUMA(S) { \
    _Pragma("unroll") \
    for (int i = 0; i < 4; ++i) { \
        s0 = fmaf(a##S##0[i], sigf(u0 + v##S##0[i]), s0); \
        s0 = fmaf(a##S##1[i], sigf(u0 + v##S##1[i]), s0); \
        s1 = fmaf(b##S##0[i], sigf(u1 + v##S##0[i]), s1); \
        s1 = fmaf(b##S##1[i], sigf(u1 + v##S##1[i]), s1); } }

    // ---------------- phase A: full-row sums, pipelined ------------------
    float s0 = 0.f, s1 = 0.f;
    LDA(A, 0)    LDA(B, 512)
    SUMA(A)      LDA(A, 1024)
    SUMA(B)      LDA(B, 1536)
    SUMA(A)      LDA(A, 2048)
    SUMA(B)      LDA(B, 2560)
    SUMA(A)      LDA(A, 3072)
    SUMA(B)      LDA(B, 3584)
    SUMA(A)      SUMA(B)

#pragma unroll
    for (int off = 32; off; off >>= 1) {
        s0 += __shfl_down(s0, off);
        s1 += __shfl_down(s1, off);
    }
    s0 = __shfl(s0, 0);
    s1 = __shfl(s1, 0);
    const float ir0 = __builtin_amdgcn_rcpf(s0 + 1e-10f);
    const float ir1 = __builtin_amdgcn_rcpf(s1 + 1e-10f);

    // ---------------- phase B: normalize + P strip + MFMA ----------------
    const int cg = wave & 3;             // output channel group (16 ch)
    const int kh = wave >> 2;            // k-half of the 2048 strip
    const short* hpbase = hT + ((size_t)(b * CC + cg * 16 + m16)) * NN + kh * 1024;

    floatx4 acc = (floatx4){0.f, 0.f, 0.f, 0.f};

#define PB(S, JG, JL) { \
    const int j_  = (JG) + lane * 8; \
    const int jl_ = (JL) + lane * 8; \
    floatx4 o00, o01, o10, o11; short8 p0, p1; \
    _Pragma("unroll") \
    for (int i = 0; i < 4; ++i) { \
        float x0 = a##S##0[i] * sigf(u0 + v##S##0[i]) * ir0; \
        float x1 = a##S##1[i] * sigf(u0 + v##S##1[i]) * ir0; \
        float y0 = b##S##0[i] * sigf(u1 + v##S##0[i]) * ir1; \
        float y1 = b##S##1[i] * sigf(u1 + v##S##1[i]) * ir1; \
        o00[i] = x0; o01[i] = x1; o10[i] = y0; o11[i] = y1; \
        p0[i] = f2bf(x0); p0[4 + i] = f2bf(x1); \
        p1[i] = f2bf(y0); p1[4 + i] = f2bf(y1); } \
    __builtin_nontemporal_store(o00, (floatx4*)(o0p + j_)); \
    __builtin_nontemporal_store(o01, (floatx4*)(o0p + j_ + 4)); \
    __builtin_nontemporal_store(o10, (floatx4*)(o1p + j_)); \
    __builtin_nontemporal_store(o11, (floatx4*)(o1p + j_ + 4)); \
    *(short8*)&P[r0][jl_]     = p0; \
    *(short8*)&P[r0 + 1][jl_] = p1; }

#define MMH(JB) { \
    const short* hq = hpbase + (JB); \
    _Pragma("unroll 8") \
    for (int s2 = 0; s2 < 32; ++s2) { \
        const short8 Af = *(const short8*)&P[m16][kh * 1024 + s2 * 32 + quad * 8]; \
        const short8 Bf = *(const short8*)(hq + s2 * 32 + quad * 8); \
        acc = __builtin_amdgcn_mfma_f32_16x16x32_bf16(Af, Bf, acc, 0, 0, 0); } }

    // ----- half 0: j in [0, 2048) -----
    LDA(A, 0)           LDA(B, 512)
    PB(A, 0, 0)         LDA(A, 1024)
    PB(B, 512, 512)     LDA(B, 1536)
    PB(A, 1024, 1024)   PB(B, 1536, 1536)
    // prefetch half 1's first chunks across the barrier + MFMA phase
    LDA(A, 2048)        LDA(B, 2560)
    lbar();
    MMH(0)
    lbar();

    // ----- half 1: j in [2048, 4096) -----
    PB(A, 2048, 0)      LDA(A, 3072)
    PB(B, 2560, 512)    LDA(B, 3584)
    PB(A, 3072, 1024)   PB(B, 3584, 1536)
    lbar();
    MMH(2048)

#undef LDA
#undef SUMA
#undef PB
#undef MMH

    // ---------------- epilogue: pair (cg, kh) add, direct store ----------
    if (kh == 1) {
#pragma unroll
        for (int i = 0; i < 4; ++i) red[cg][quad * 4 + i][m16] = acc[i];
    }
    __syncthreads();
    if (kh == 0) {
#pragma unroll
        for (int i = 0; i < 4; ++i) {
            const float sfin = acc[i] + red[cg][quad * 4 + i][m16];
            hout[((size_t)(b * NN + n0 + quad * 4 + i)) * CC + cg * 16 + m16] = sfin;
        }
    }
}

// ---------------------------------------------------------------------------
extern "C" void kernel_launch(void* const* d_in, const int* in_sizes, int n_in,
                              void* d_out, int out_size, void* d_ws, size_t ws_size,
                              hipStream_t stream) {
    (void)in_sizes; (void)n_in; (void)out_size; (void)ws_size;
    const float* x   = (const float*)d_in[0];
    const float* adj = (const float*)d_in[1];
    const float* W1  = (const float*)d_in[2];
    const float* b1  = (const float*)d_in[3];
    const float* W2  = (const float*)d_in[4];
    const float* b2  = (const float*)d_in[5];
    const float* Wa  = (const float*)d_in[6];
    const float* ba  = (const float*)d_in[7];

    float* hout = (float*)d_out;                       // [B,N,64]
    float* aout = hout + (size_t)BB * NN * CC;         // [B,N,N]

    char* ws = (char*)d_ws;
    short* hT = (short*)ws;                            // bf16 [B][64][N]
    float* u  = (float*)(ws + (size_t)BB * CC * NN * sizeof(short));
    float* vv = u + BB * NN;

    feat_v3<<<BB * NN / 16, 256, 0, stream>>>(x, W1, b1, W2, b2, Wa, ba, hT, u, vv);
    attn_v5<<<BB * NN / 16, 512, 0, stream>>>(adj, u, vv, hT, hout, aout);
}

// Round 4
// 310.847 us; speedup vs baseline: 1.2202x; 1.2202x over previous
//
#include <hip/hip_runtime.h>

#define BB 2
#define NN 4096
#define CIN 128
#define CC 64

typedef __attribute__((ext_vector_type(4))) float floatx4;
typedef __attribute__((ext_vector_type(8))) short short8;

__device__ __forceinline__ short f2bf(float f) {
    unsigned u = __float_as_uint(f);
    u += 0x7fffu + ((u >> 16) & 1u);   // RNE
    return (short)(u >> 16);
}

// sigmoid via v_exp_f32 + v_rcp_f32 (avoid precise-division expansion)
__device__ __forceinline__ float sigf(float x) {
    return __builtin_amdgcn_rcpf(1.0f + __expf(-x));
}

// ---------------------------------------------------------------------------
// feat_v3: h = relu(relu(x@W1+b1)@W2+b2); u,v scalars; hT bf16 transposed.
// 16 rows/block, 256 threads, grid 512. hT written via LDS transpose tile
// -> coalesced short8 stores.
// ---------------------------------------------------------------------------
__global__ __launch_bounds__(256) void feat_v3(
    const float* __restrict__ x, const float* __restrict__ W1,
    const float* __restrict__ b1, const float* __restrict__ W2,
    const float* __restrict__ b2, const float* __restrict__ Wa,
    const float* __restrict__ ba,
    short* __restrict__ hT, float* __restrict__ u, float* __restrict__ v)
{
    __shared__ float W1s[CIN * CC];      // 32KB
    __shared__ float W2s[CC * CC];       // 16KB
    __shared__ float xs[16 * 132];       // 8.4KB padded
    __shared__ float h1s[16 * 68];       // 4.4KB padded
    __shared__ __align__(16) short hs[CC][16];  // 2KB bf16 transpose tile

    const int t = threadIdx.x;
    const int row0 = blockIdx.x * 16;

    {
        const floatx4* s1 = (const floatx4*)W1;
        floatx4* d1 = (floatx4*)W1s;
        for (int i = t; i < CIN * CC / 4; i += 256) d1[i] = s1[i];
        const floatx4* s2 = (const floatx4*)W2;
        floatx4* d2 = (floatx4*)W2s;
        for (int i = t; i < CC * CC / 4; i += 256) d2[i] = s2[i];
        const floatx4* sx = (const floatx4*)(x + (size_t)row0 * CIN);
        for (int i = t; i < 16 * CIN / 4; i += 256) {
            int rw = i >> 5, c4 = i & 31;
            *(floatx4*)(xs + rw * 132 + c4 * 4) = sx[i];
        }
    }
    __syncthreads();

    const int n  = t >> 4;       // 0..15 local row
    const int cg = t & 15;
    const int c0 = cg * 4;

    float acc[4];
#pragma unroll
    for (int i = 0; i < 4; i++) acc[i] = b1[c0 + i];
    for (int k = 0; k < CIN; k++) {
        float a = xs[n * 132 + k];
        const floatx4 w = *(const floatx4*)&W1s[k * CC + c0];
#pragma unroll
        for (int i = 0; i < 4; i++) acc[i] = fmaf(a, w[i], acc[i]);
    }
#pragma unroll
    for (int i = 0; i < 4; i++) h1s[n * 68 + c0 + i] = fmaxf(acc[i], 0.0f);
    __syncthreads();

    float acc2[4];
#pragma unroll
    for (int i = 0; i < 4; i++) acc2[i] = b2[c0 + i];
    for (int k = 0; k < CC; k++) {
        float a = h1s[n * 68 + k];
        const floatx4 w = *(const floatx4*)&W2s[k * CC + c0];
#pragma unroll
        for (int i = 0; i < 4; i++) acc2[i] = fmaf(a, w[i], acc2[i]);
    }
#pragma unroll
    for (int i = 0; i < 4; i++) acc2[i] = fmaxf(acc2[i], 0.0f);

    // stage bf16 transpose tile in LDS
#pragma unroll
    for (int i = 0; i < 4; i++) hs[c0 + i][n] = f2bf(acc2[i]);

    float pu = 0.0f, pv = 0.0f;
#pragma unroll
    for (int i = 0; i < 4; i++) {
        pu = fmaf(acc2[i], Wa[c0 + i], pu);
        pv = fmaf(acc2[i], Wa[CC + c0 + i], pv);
    }
    pu += __shfl_down(pu, 8, 16); pv += __shfl_down(pv, 8, 16);
    pu += __shfl_down(pu, 4, 16); pv += __shfl_down(pv, 4, 16);
    pu += __shfl_down(pu, 2, 16); pv += __shfl_down(pv, 2, 16);
    pu += __shfl_down(pu, 1, 16); pv += __shfl_down(pv, 1, 16);

    const int grow = row0 + n;
    if (cg == 0) { u[grow] = pu + ba[0]; v[grow] = pv; }

    __syncthreads();
    // coalesced hT write: 128 threads x short8 (16B), 2 per channel row
    if (t < 128) {
        const int c  = t >> 1;
        const int hf = t & 1;
        const int b   = row0 >> 12;
        const int nn0 = row0 & (NN - 1);
        *(short8*)(hT + ((size_t)(b * CC + c)) * NN + nn0 + hf * 8) =
            *(const short8*)&hs[c][hf * 8];
    }
}

// ---------------------------------------------------------------------------
// rowsum_v2: r[row] = sum_j sigmoid(u[row]+v[j]) * adj[row][j]
// one WAVE per row, 4 rows/block, grid 2048. Cold read of adj warms L3
// for attn_v6 (adj = 134 MB < 256 MB Infinity Cache).
// ---------------------------------------------------------------------------
__global__ __launch_bounds__(256) void rowsum_v2(
    const float* __restrict__ adj, const float* __restrict__ u,
    const float* __restrict__ v, float* __restrict__ r)
{
    const int wave = threadIdx.x >> 6;
    const int lane = threadIdx.x & 63;
    const int row  = blockIdx.x * 4 + wave;
    const int b = row >> 12;
    const float un = u[row];                 // already includes ba
    const floatx4* arow = (const floatx4*)(adj + (size_t)row * NN);
    const floatx4* vb = (const floatx4*)(v + b * NN);

    float p0 = 0.f, p1 = 0.f, p2 = 0.f, p3 = 0.f;
#pragma unroll 4
    for (int i = 0; i < 16; i++) {
        int idx = lane + i * 64;
        floatx4 a4 = arow[idx];
        floatx4 v4 = vb[idx];
        p0 = fmaf(a4.x, sigf(un + v4.x), p0);
        p1 = fmaf(a4.y, sigf(un + v4.y), p1);
        p2 = fmaf(a4.z, sigf(un + v4.z), p2);
        p3 = fmaf(a4.w, sigf(un + v4.w), p3);
    }
    float p = (p0 + p1) + (p2 + p3);
#pragma unroll
    for (int off = 32; off > 0; off >>= 1) p += __shfl_down(p, off);
    if (lane == 0) r[row] = p;
}

// ---------------------------------------------------------------------------
// attn_v6: v2 structure + named 2-stage register pipeline + NT aout stores.
// Block = 16 rows x 1024 j (4 waves x 256 j). Grid 2048 -> up to 4 blocks/CU
// (launch_bounds(256,4): VGPR cap 128, pipeline needs ~110 -> no spills,
// unlike v5's 64-cap spill disaster; unlike v2's VGPR=32 collapsed pipe).
// adj reads hit L3 (rowsum warmed it; NT aout stores don't evict).
// Cross-wave LDS reduce, then 4 atomics/thread for hout.
// ---------------------------------------------------------------------------
__global__ __launch_bounds__(256, 4) void attn_v6(
    const float* __restrict__ adj, const float* __restrict__ u,
    const float* __restrict__ v, const float* __restrict__ r,
    const short* __restrict__ hT,
    float* __restrict__ hout, float* __restrict__ aout)
{
    __shared__ float red[4][16][CC + 1];   // 16.6 KB

    const int wave = threadIdx.x >> 6;
    const int lane = threadIdx.x & 63;
    const int quad = lane >> 4;
    const int m16  = lane & 15;

    const int tile = blockIdx.x >> 2;      // 0..511 row-tile
    const int jq   = blockIdx.x & 3;       // j quarter
    const int row0 = tile * 16;
    const int b  = row0 >> 12;
    const int n0 = row0 & (NN - 1);
    const int n  = n0 + m16;

    const size_t rowbase = ((size_t)(b * NN + n)) * NN;
    const float un    = u[b * NN + n];     // includes ba
    const float inv_r = __builtin_amdgcn_rcpf(r[b * NN + n] + 1e-10f);
    const float* vb = v + b * NN;
    const float* ap_base = adj + rowbase;
    float*       op_base = aout + rowbase;
    const short* hp0 = hT + ((size_t)(b * CC +  0 + m16)) * NN;
    const short* hp1 = hT + ((size_t)(b * CC + 16 + m16)) * NN;
    const short* hp2 = hT + ((size_t)(b * CC + 32 + m16)) * NN;
    const short* hp3 = hT + ((size_t)(b * CC + 48 + m16)) * NN;

    floatx4 acc[4];
#pragma unroll
    for (int g = 0; g < 4; g++) acc[g] = (floatx4){0.f, 0.f, 0.f, 0.f};

    const int jb0 = jq * 1024 + wave * 256 + quad * 8;

    // named 2-stage pipeline: 32 VGPR per stage
    floatx4 a0A, a1A, v0A, v1A; short8 h0A, h1A, h2A, h3A;
    floatx4 a0B, a1B, v0B, v1B; short8 h0B, h1B, h2B, h3B;

#define LOADST(S, jb) { \
    a0##S = *(const floatx4*)(ap_base + (jb));      \
    a1##S = *(const floatx4*)(ap_base + (jb) + 4);  \
    v0##S = *(const floatx4*)(vb + (jb));           \
    v1##S = *(const floatx4*)(vb + (jb) + 4);       \
    h0##S = *(const short8*)(hp0 + (jb));           \
    h1##S = *(const short8*)(hp1 + (jb));           \
    h2##S = *(const short8*)(hp2 + (jb));           \
    h3##S = *(const short8*)(hp3 + (jb)); }

#define COMPST(S, jb) { \
    float av[8] = {a0##S.x, a0##S.y, a0##S.z, a0##S.w, a1##S.x, a1##S.y, a1##S.z, a1##S.w}; \
    float vv[8] = {v0##S.x, v0##S.y, v0##S.z, v0##S.w, v1##S.x, v1##S.y, v1##S.z, v1##S.w}; \
    floatx4 o0, o1; short8 af; \
    _Pragma("unroll") \
    for (int i = 0; i < 8; ++i) { \
        float s_ = av[i] * sigf(un + vv[i]) * inv_r; \
        if (i < 4) o0[i] = s_; else o1[i - 4] = s_; \
        af[i] = f2bf(s_); } \
    __builtin_nontemporal_store(o0, (floatx4*)(op_base + (jb)));     \
    __builtin_nontemporal_store(o1, (floatx4*)(op_base + (jb) + 4)); \
    acc[0] = __builtin_amdgcn_mfma_f32_16x16x32_bf16(af, h0##S, acc[0], 0, 0, 0); \
    acc[1] = __builtin_amdgcn_mfma_f32_16x16x32_bf16(af, h1##S, acc[1], 0, 0, 0); \
    acc[2] = __builtin_amdgcn_mfma_f32_16x16x32_bf16(af, h2##S, acc[2], 0, 0, 0); \
    acc[3] = __builtin_amdgcn_mfma_f32_16x16x32_bf16(af, h3##S, acc[3], 0, 0, 0); }

    LOADST(A, jb0)
    LOADST(B, jb0 + 32)
#pragma unroll
    for (int s = 0; s < 8; s += 2) {
        COMPST(A, jb0 + s * 32)
        if (s + 2 < 8) LOADST(A, jb0 + (s + 2) * 32)
        COMPST(B, jb0 + (s + 1) * 32)
        if (s + 3 < 8) LOADST(B, jb0 + (s + 3) * 32)
    }
#undef LOADST
#undef COMPST

    // C/D layout: col(m16)=channel, row(quad*4+i)=adj row. Stage to LDS.
#pragma unroll
    for (int g = 0; g < 4; g++) {
        const int c = g * 16 + m16;
#pragma unroll
        for (int i = 0; i < 4; i++)
            red[wave][quad * 4 + i][c] = acc[g][i];
    }
    __syncthreads();

    // 256 threads x 4 elems cover 16x64; sum 4 waves, one atomic per elem.
#pragma unroll
    for (int e = 0; e < 4; e++) {
        const int idx = threadIdx.x * 4 + e;
        const int rr = idx >> 6;
        const int c  = idx & 63;
        float s = red[0][rr][c] + red[1][rr][c] + red[2][rr][c] + red[3][rr][c];
        atomicAdd(&hout[((size_t)(b * NN + n0 + rr)) * CC + c], s);
    }
}

// ---------------------------------------------------------------------------
extern "C" void kernel_launch(void* const* d_in, const int* in_sizes, int n_in,
                              void* d_out, int out_size, void* d_ws, size_t ws_size,
                              hipStream_t stream) {
    (void)in_sizes; (void)n_in; (void)out_size; (void)ws_size;
    const float* x   = (const float*)d_in[0];
    const float* adj = (const float*)d_in[1];
    const float* W1  = (const float*)d_in[2];
    const float* b1  = (const float*)d_in[3];
    const float* W2  = (const float*)d_in[4];
    const float* b2  = (const float*)d_in[5];
    const float* Wa  = (const float*)d_in[6];
    const float* ba  = (const float*)d_in[7];

    float* hout = (float*)d_out;                       // [B,N,64]
    float* aout = hout + (size_t)BB * NN * CC;         // [B,N,N]

    char* ws = (char*)d_ws;
    short* hT = (short*)ws;                            // bf16 [B][64][N]
    float* u  = (float*)(ws + (size_t)BB * CC * NN * sizeof(short));
    float* vv = u + BB * NN;
    float* r  = vv + BB * NN;

    hipMemsetAsync(hout, 0, (size_t)BB * NN * CC * sizeof(float), stream);
    feat_v3<<<BB * NN / 16, 256, 0, stream>>>(x, W1, b1, W2, b2, Wa, ba, hT, u, vv);
    rowsum_v2<<<BB * NN / 4, 256, 0, stream>>>(adj, u, vv, r);
    attn_v6<<<(BB * NN / 16) * 4, 256, 0, stream>>>(adj, u, vv, r, hT, hout, aout);
}